// Round 11
// baseline (44.162 us; speedup 1.0000x reference)
//
#include <hip/hip_runtime.h>
#include <hip/hip_fp16.h>

// Box-log-edge, v10: v9 + Phase-A loads hoisted (all slab rows loaded into
// registers up-front, sched_barrier(0) pins issue order) to hide L2/L3 latency.
// Phase A (228 thr = 38 col-chunks x 6 row-groups): rolling 6-row window pair,
//   fp16 stores of S6 (+0.06) and full11 (+0.11). bot6[r] == S6[r+5].
// Phase B (256 thr x 2 independent 8-px strips): ds_read b128/b64, f16->f32,
//   register sliding windows, log2-domain ratio + L2 norm, float4 stores.

#define N   512
#define SH  88            // S6A stride in halfs
#define SF  80            // fulA stride in halfs
#define LN2 0.69314718056f

typedef __fp16 h2  __attribute__((ext_vector_type(2)));
typedef __fp16 h4v __attribute__((ext_vector_type(4)));
typedef __fp16 h8v __attribute__((ext_vector_type(8)));

__device__ __forceinline__ float2 f2add(float2 a, float2 b){ return make_float2(a.x+b.x, a.y+b.y); }
__device__ __forceinline__ float2 f2sub(float2 a, float2 b){ return make_float2(a.x-b.x, a.y-b.y); }

// Load halfs [base .. base+19] into f32 t[0..19], registers only.
__device__ __forceinline__ void load20(const __half* __restrict__ arr, int base, float* __restrict__ t) {
    h8v a = *(const h8v*)(arr + base);
    h8v b = *(const h8v*)(arr + base + 8);
    h4v c = *(const h4v*)(arr + base + 16);
    #pragma unroll
    for (int j = 0; j < 8; ++j) t[j]      = (float)a[j];
    #pragma unroll
    for (int j = 0; j < 8; ++j) t[8 + j]  = (float)b[j];
    #pragma unroll
    for (int j = 0; j < 4; ++j) t[16 + j] = (float)c[j];
}

__global__ __launch_bounds__(256, 7) void boxlog_kernel(
    const float* __restrict__ x, float* __restrict__ out)
{
    __shared__ __align__(16) __half S6A [69*SH];   // S6[r] = padded rows r..r+5 (+0.06)
    __shared__ __align__(16) __half fulA[64*SF];   // full11[r] = rows r..r+10 (+0.11)

    const int tid = threadIdx.x;
    // XCD-aware swizzle over 4096 blocks: each XCD gets 8 contiguous images
    const int wg  = blockIdx.x;
    const int sw  = (wg & 7) * 512 + (wg >> 3);
    const int bz  = sw >> 6;          // image 0..63
    const int rem = sw & 63;
    const int by  = rem >> 3;         // 0..7
    const int bx  = rem & 7;          // 0..7
    const int X0 = bx * 64, Y0 = by * 64;
    const float* __restrict__ xb   = x   + (size_t)bz * ((size_t)N * N);
    float* __restrict__       outb = out + (size_t)bz * ((size_t)N * N);

    // ---------------- Phase A: rolling S6 + full11 (fp16 to LDS) ------------
    // 38 col-chunks (2 cols, local halfs 2ch..2ch+1 <-> global X0-6+2ch)
    // x 6 row-groups. Groups 0-4: 21 rows, 11 S6 + 11 full; group 5: 19 rows,
    // 14 S6 + 9 full. ALL rows loaded up-front, then sums (latency batched).
    if (tid < 228) {
        const int rg = tid / 38;         // 0..5
        const int ch = tid - rg * 38;    // 0..37
        const int f0 = rg * 11;          // first padded row of this slab
        const int gc = X0 - 6 + 2 * ch;  // even -> 8B-aligned float2

        auto body = [&](auto loadrow, auto NF, auto NS) {
            constexpr int nf = decltype(NF)::value;   // full rows written
            constexpr int ns = decltype(NS)::value;   // S6 rows written
            float2 t[21];
            #pragma unroll
            for (int j = 0; j < 10 + nf; ++j) t[j] = loadrow(j);   // ALL loads up-front
            __builtin_amdgcn_sched_barrier(0);                     // pin: no sinking
            float2 lo = f2add(f2add(f2add(t[0],t[1]), f2add(t[2],t[3])), f2add(t[4],t[5]));
            float2 hi = f2add(f2add(f2add(t[5],t[6]), f2add(t[7],t[8])), f2add(t[9],t[10]));
            {
                float2 fu = f2sub(f2add(lo, hi), t[5]);
                *(h2*)&S6A [f0 * SH + 2 * ch] = __builtin_amdgcn_cvt_pkrtz(lo.x + 0.06f, lo.y + 0.06f);
                *(h2*)&fulA[f0 * SF + 2 * ch] = __builtin_amdgcn_cvt_pkrtz(fu.x + 0.11f, fu.y + 0.11f);
            }
            #pragma unroll
            for (int k = 1; k < ns; ++k) {
                lo = f2sub(f2add(lo, t[k+5]), t[k-1]);
                *(h2*)&S6A[(f0 + k) * SH + 2 * ch] = __builtin_amdgcn_cvt_pkrtz(lo.x + 0.06f, lo.y + 0.06f);
                if (k < nf) {
                    hi = f2sub(f2add(hi, t[k+10]), t[k+4]);
                    float2 fu = f2sub(f2add(lo, hi), t[k+5]);
                    *(h2*)&fulA[(f0 + k) * SF + 2 * ch] = __builtin_amdgcn_cvt_pkrtz(fu.x + 0.11f, fu.y + 0.11f);
                }
            }
        };

        if (by >= 1 && by <= 6 && bx >= 1 && bx <= 6) {
            auto lr = [&](int j) {
                return *(const float2*)(xb + (size_t)(Y0 - 5 + f0 + j) * N + gc);
            };
            if (rg < 5) body(lr, std::integral_constant<int,11>{}, std::integral_constant<int,11>{});
            else        body(lr, std::integral_constant<int, 9>{}, std::integral_constant<int,14>{});
        } else {
            const bool vec = (gc >= 0) && (gc <= N - 2);
            auto lr = [&](int j) {
                int gr = Y0 - 5 + f0 + j;
                gr = gr < 0 ? -gr : (gr > N-1 ? 2*(N-1) - gr : gr);
                const float* rowp = xb + (size_t)gr * N;
                if (vec) return *(const float2*)(rowp + gc);
                int c0 = gc, c1 = gc + 1;
                c0 = c0 < 0 ? -c0 : (c0 > N-1 ? 2*(N-1) - c0 : c0);
                c1 = c1 < 0 ? -c1 : (c1 > N-1 ? 2*(N-1) - c1 : c1);
                return make_float2(rowp[c0], rowp[c1]);
            };
            if (rg < 5) body(lr, std::integral_constant<int,11>{}, std::integral_constant<int,11>{});
            else        body(lr, std::integral_constant<int, 9>{}, std::integral_constant<int,14>{});
        }
    }
    __syncthreads();

    // ---------------- Phase B: 2 independent 8-px sliding-window strips ------
    // t[i] <-> local col 8*tx + i ; out col o = 8*tx+p uses window t[p+1..p+11]
    const int tx = tid & 7;       // 8 strips of 8 px
    const int ty = tid >> 3;      // 0..31 -> rows ty and ty+32
    #pragma unroll
    for (int s = 0; s < 2; ++s) {
        const int row   = ty + 32 * s;
        const int baseS = row * SH + 8 * tx;
        const int baseF = row * SF + 8 * tx;

        float gy1[8], ly[8];
        {   // top6 = S6[row] -> gy1 windows (11-wide)
            float t[20];
            load20(S6A, baseS, t);
            float g = ((t[1]+t[2])+(t[3]+t[4]))+((t[5]+t[6])+(t[7]+t[8]))+((t[9]+t[10])+t[11]);
            gy1[0] = g;
            #pragma unroll
            for (int p = 1; p < 8; ++p) { g += t[p+11] - t[p]; gy1[p] = g; }
        }
        {   // bot6 = S6[row+5] -> gy2 windows, fold into log2 ratio
            float t[20];
            load20(S6A, baseS + 5*SH, t);
            float g = ((t[1]+t[2])+(t[3]+t[4]))+((t[5]+t[6])+(t[7]+t[8]))+((t[9]+t[10])+t[11]);
            ly[0] = __builtin_amdgcn_logf(gy1[0]) - __builtin_amdgcn_logf(g);
            #pragma unroll
            for (int p = 1; p < 8; ++p) {
                g += t[p+11] - t[p];
                ly[p] = __builtin_amdgcn_logf(gy1[p]) - __builtin_amdgcn_logf(g);
            }
        }
        {   // full11 -> gx window pair (6-wide), combine + store
            float t[20];
            load20(fulA, baseF, t);
            float g1 = ((t[1]+t[2])+(t[3]+t[4]))+(t[5]+t[6]);
            float g2 = ((t[6]+t[7])+(t[8]+t[9]))+(t[10]+t[11]);
            float r8[8];
            #pragma unroll
            for (int p = 0; p < 8; ++p) {
                if (p) {
                    g1 += t[p+6]  - t[p];
                    g2 += t[p+11] - t[p+5];
                }
                float lx = __builtin_amdgcn_logf(g1) - __builtin_amdgcn_logf(g2);
                r8[p] = LN2 * __builtin_amdgcn_sqrtf(lx*lx + ly[p]*ly[p]);
            }
            float* op = outb + (size_t)(Y0 + row) * N + X0 + tx * 8;
            *(float4*)op       = make_float4(r8[0], r8[1], r8[2], r8[3]);
            *(float4*)(op + 4) = make_float4(r8[4], r8[5], r8[6], r8[7]);
        }
    }
}

extern "C" void kernel_launch(void* const* d_in, const int* in_sizes, int n_in,
                              void* d_out, int out_size, void* d_ws, size_t ws_size,
                              hipStream_t stream) {
    const float* x = (const float*)d_in[0];  // (64,1,512,512) fp32
    float* out = (float*)d_out;              // (64,1,512,512) fp32
    dim3 grid(8 * 8 * 64);                   // 64x64 tiles, swizzled in-kernel
    dim3 block(256);
    boxlog_kernel<<<grid, block, 0, stream>>>(x, out);
}

// Round 12
// 36.366 us; speedup vs baseline: 1.2144x; 1.2144x over previous
//
#include <hip/hip_runtime.h>

// Box-log-edge, v12: v9 structure with f32 LDS (kills ~120 f16 cvts/thread).
//  - S6A/fulA stride 76 floats (304B, bank-uniform for b128), LDS 40.4KB -> 4 blocks/CU
// Phase A (228 thr = 38 col-chunks x 6 row-groups): rolling 6-row window pair,
//   float2 stores of S6 (+0.06) and full11 (+0.11). bot6[r] == S6[r+5].
// Phase B (256 thr x 2 independent 8-px strips): 5x ds_read_b128 per pass,
//   register sliding windows, log-domain ratio + L2 norm, float4 stores.

#define N   512
#define SS  76            // LDS row stride in floats (both arrays)
#define LN2 0.69314718056f

__device__ __forceinline__ float2 f2add(float2 a, float2 b){ return make_float2(a.x+b.x, a.y+b.y); }
__device__ __forceinline__ float2 f2sub(float2 a, float2 b){ return make_float2(a.x-b.x, a.y-b.y); }

// Load floats [base .. base+19] into t[0..19] via 5x b128.
__device__ __forceinline__ void load20(const float* __restrict__ arr, int base, float* __restrict__ t) {
    #pragma unroll
    for (int i = 0; i < 5; ++i)
        *(float4*)&t[4*i] = *(const float4*)&arr[base + 4*i];
}

__global__ __launch_bounds__(256, 4) void boxlog_kernel(
    const float* __restrict__ x, float* __restrict__ out)
{
    __shared__ __align__(16) float S6A [69*SS];   // S6[r] = padded rows r..r+5 (+0.06)
    __shared__ __align__(16) float fulA[64*SS];   // full11[r] = rows r..r+10 (+0.11)

    const int tid = threadIdx.x;
    // XCD-aware swizzle over 4096 blocks: each XCD gets 8 contiguous images
    const int wg  = blockIdx.x;
    const int sw  = (wg & 7) * 512 + (wg >> 3);
    const int bz  = sw >> 6;          // image 0..63
    const int rem = sw & 63;
    const int by  = rem >> 3;         // 0..7
    const int bx  = rem & 7;          // 0..7
    const int X0 = bx * 64, Y0 = by * 64;
    const float* __restrict__ xb   = x   + (size_t)bz * ((size_t)N * N);
    float* __restrict__       outb = out + (size_t)bz * ((size_t)N * N);

    // ---------------- Phase A: rolling S6 + full11 (f32 to LDS) -------------
    // 38 col-chunks (2 cols, local floats 2ch..2ch+1 <-> global X0-6+2ch)
    // x 6 row-groups. Groups 0-4: 11 full, 11 S6; group 5: 9 full, 14 S6.
    if (tid < 228) {
        const int rg = tid / 38;         // 0..5
        const int ch = tid - rg * 38;    // 0..37
        const int f0 = rg * 11;          // first padded row of this slab
        const int gc = X0 - 6 + 2 * ch;  // even -> 8B-aligned float2

        auto body = [&](auto loadrow, auto NF, auto NS) {
            constexpr int nf = decltype(NF)::value;   // full rows written
            constexpr int ns = decltype(NS)::value;   // S6 rows written
            float2 t[21];
            #pragma unroll
            for (int j = 0; j < 11; ++j) t[j] = loadrow(j);
            float2 lo = f2add(f2add(f2add(t[0],t[1]), f2add(t[2],t[3])), f2add(t[4],t[5]));
            float2 hi = f2add(f2add(f2add(t[5],t[6]), f2add(t[7],t[8])), f2add(t[9],t[10]));
            {
                float2 fu = f2sub(f2add(lo, hi), t[5]);
                *(float2*)&S6A [f0 * SS + 2 * ch] = make_float2(lo.x + 0.06f, lo.y + 0.06f);
                *(float2*)&fulA[f0 * SS + 2 * ch] = make_float2(fu.x + 0.11f, fu.y + 0.11f);
            }
            #pragma unroll
            for (int k = 1; k < ns; ++k) {
                if (k < nf) t[k+10] = loadrow(k + 10);
                lo = f2sub(f2add(lo, t[k+5]), t[k-1]);
                *(float2*)&S6A[(f0 + k) * SS + 2 * ch] = make_float2(lo.x + 0.06f, lo.y + 0.06f);
                if (k < nf) {
                    hi = f2sub(f2add(hi, t[k+10]), t[k+4]);
                    float2 fu = f2sub(f2add(lo, hi), t[k+5]);
                    *(float2*)&fulA[(f0 + k) * SS + 2 * ch] = make_float2(fu.x + 0.11f, fu.y + 0.11f);
                }
            }
        };

        if (by >= 1 && by <= 6 && bx >= 1 && bx <= 6) {
            auto lr = [&](int j) {
                return *(const float2*)(xb + (size_t)(Y0 - 5 + f0 + j) * N + gc);
            };
            if (rg < 5) body(lr, std::integral_constant<int,11>{}, std::integral_constant<int,11>{});
            else        body(lr, std::integral_constant<int, 9>{}, std::integral_constant<int,14>{});
        } else {
            const bool vec = (gc >= 0) && (gc <= N - 2);
            auto lr = [&](int j) {
                int gr = Y0 - 5 + f0 + j;
                gr = gr < 0 ? -gr : (gr > N-1 ? 2*(N-1) - gr : gr);
                const float* rowp = xb + (size_t)gr * N;
                if (vec) return *(const float2*)(rowp + gc);
                int c0 = gc, c1 = gc + 1;
                c0 = c0 < 0 ? -c0 : (c0 > N-1 ? 2*(N-1) - c0 : c0);
                c1 = c1 < 0 ? -c1 : (c1 > N-1 ? 2*(N-1) - c1 : c1);
                return make_float2(rowp[c0], rowp[c1]);
            };
            if (rg < 5) body(lr, std::integral_constant<int,11>{}, std::integral_constant<int,11>{});
            else        body(lr, std::integral_constant<int, 9>{}, std::integral_constant<int,14>{});
        }
    }
    __syncthreads();

    // ---------------- Phase B: 2 independent 8-px sliding-window strips ------
    // t[i] <-> local col 8*tx + i ; out col o = 8*tx+p uses window t[p+1..p+11]
    const int tx = tid & 7;       // 8 strips of 8 px
    const int ty = tid >> 3;      // 0..31 -> rows ty and ty+32
    #pragma unroll
    for (int s = 0; s < 2; ++s) {
        const int row  = ty + 32 * s;
        const int base = row * SS + 8 * tx;

        float gy1[8], ly[8];
        {   // top6 = S6[row] -> gy1 windows (11-wide)
            float t[20];
            load20(S6A, base, t);
            float g = ((t[1]+t[2])+(t[3]+t[4]))+((t[5]+t[6])+(t[7]+t[8]))+((t[9]+t[10])+t[11]);
            gy1[0] = g;
            #pragma unroll
            for (int p = 1; p < 8; ++p) { g += t[p+11] - t[p]; gy1[p] = g; }
        }
        {   // bot6 = S6[row+5] -> gy2 windows, fold into log ratio
            float t[20];
            load20(S6A, base + 5*SS, t);
            float g = ((t[1]+t[2])+(t[3]+t[4]))+((t[5]+t[6])+(t[7]+t[8]))+((t[9]+t[10])+t[11]);
            ly[0] = __builtin_amdgcn_logf(gy1[0]) - __builtin_amdgcn_logf(g);
            #pragma unroll
            for (int p = 1; p < 8; ++p) {
                g += t[p+11] - t[p];
                ly[p] = __builtin_amdgcn_logf(gy1[p]) - __builtin_amdgcn_logf(g);
            }
        }
        {   // full11 -> gx window pair (6-wide), combine + store
            float t[20];
            load20(fulA, base, t);
            float g1 = ((t[1]+t[2])+(t[3]+t[4]))+(t[5]+t[6]);
            float g2 = ((t[6]+t[7])+(t[8]+t[9]))+(t[10]+t[11]);
            float r8[8];
            #pragma unroll
            for (int p = 0; p < 8; ++p) {
                if (p) {
                    g1 += t[p+6]  - t[p];
                    g2 += t[p+11] - t[p+5];
                }
                float lx = __builtin_amdgcn_logf(g1) - __builtin_amdgcn_logf(g2);
                r8[p] = LN2 * __builtin_amdgcn_sqrtf(lx*lx + ly[p]*ly[p]);
            }
            float* op = outb + (size_t)(Y0 + row) * N + X0 + tx * 8;
            *(float4*)op       = make_float4(r8[0], r8[1], r8[2], r8[3]);
            *(float4*)(op + 4) = make_float4(r8[4], r8[5], r8[6], r8[7]);
        }
    }
}

extern "C" void kernel_launch(void* const* d_in, const int* in_sizes, int n_in,
                              void* d_out, int out_size, void* d_ws, size_t ws_size,
                              hipStream_t stream) {
    const float* x = (const float*)d_in[0];  // (64,1,512,512) fp32
    float* out = (float*)d_out;              // (64,1,512,512) fp32
    dim3 grid(8 * 8 * 64);                   // 64x64 tiles, swizzled in-kernel
    dim3 block(256);
    boxlog_kernel<<<grid, block, 0, stream>>>(x, out);
}

// Round 13
// 33.264 us; speedup vs baseline: 1.3276x; 1.0933x over previous
//
#include <hip/hip_runtime.h>
#include <hip/hip_fp16.h>

// Box-log-edge, v13: 1-wave workgroups (decouple the Phase A->B barrier).
// Block = 64 thr = 1 wave, tile 64x16. Producer wave == consumer wave, so
// __syncthreads degenerates to in-wave waitcnt; no inter-wave coupling.
// fp16 LDS 5.9KB/block -> 27 blocks/CU.
// Phase A (38 lanes): float2 loads, rolling 6-row sums over 26 padded rows ->
//   S6[0..20] (+0.06) and full11[0..15] (+0.11) in fp16. bot6[r] == S6[r+5].
// Phase B (64 lanes x 2 strips of 8 px): 20-half loads, register sliding
//   windows, log-domain ratio + L2 norm, float4 stores.

#define N   512
#define SH  80            // LDS row stride in halfs (160B)
#define LN2 0.69314718056f

typedef __fp16 h2  __attribute__((ext_vector_type(2)));
typedef __fp16 h4v __attribute__((ext_vector_type(4)));
typedef __fp16 h8v __attribute__((ext_vector_type(8)));

__device__ __forceinline__ float2 f2add(float2 a, float2 b){ return make_float2(a.x+b.x, a.y+b.y); }
__device__ __forceinline__ float2 f2sub(float2 a, float2 b){ return make_float2(a.x-b.x, a.y-b.y); }

// Load halfs [base .. base+19] into f32 t[0..19], registers only.
__device__ __forceinline__ void load20(const __half* __restrict__ arr, int base, float* __restrict__ t) {
    h8v a = *(const h8v*)(arr + base);
    h8v b = *(const h8v*)(arr + base + 8);
    h4v c = *(const h4v*)(arr + base + 16);
    #pragma unroll
    for (int j = 0; j < 8; ++j) t[j]      = (float)a[j];
    #pragma unroll
    for (int j = 0; j < 8; ++j) t[8 + j]  = (float)b[j];
    #pragma unroll
    for (int j = 0; j < 4; ++j) t[16 + j] = (float)c[j];
}

__global__ __launch_bounds__(64, 6) void boxlog_kernel(
    const float* __restrict__ x, float* __restrict__ out)
{
    __shared__ __align__(16) __half S6A [21*SH];   // S6[r] = padded rows r..r+5 (+0.06)
    __shared__ __align__(16) __half fulA[16*SH];   // full11[r] = rows r..r+10 (+0.11)

    const int lane = threadIdx.x;
    // XCD-aware swizzle over 16384 blocks: each XCD gets 8 contiguous images
    const int wg  = blockIdx.x;
    const int sw  = (wg & 7) * 2048 + (wg >> 3);
    const int bz  = sw >> 8;          // image 0..63
    const int rem = sw & 255;
    const int by  = rem >> 3;         // 0..31 (16-row tiles)
    const int bx  = rem & 7;          // 0..7  (64-col tiles)
    const int X0 = bx * 64, Y0 = by * 16;
    const float* __restrict__ xb   = x   + (size_t)bz * ((size_t)N * N);
    float* __restrict__       outb = out + (size_t)bz * ((size_t)N * N);

    // ---------------- Phase A: rolling S6 + full11 (fp16 to LDS) ------------
    // 38 lanes x 2 cols (local halfs 2l..2l+1 <-> global X0-6+2l), 26 padded rows.
    if (lane < 38) {
        const int gc = X0 - 6 + 2 * lane;  // even -> 8B-aligned float2

        auto body = [&](auto loadrow) {
            float2 t[26];
            #pragma unroll
            for (int j = 0; j < 11; ++j) t[j] = loadrow(j);
            float2 lo = f2add(f2add(f2add(t[0],t[1]), f2add(t[2],t[3])), f2add(t[4],t[5]));
            float2 hi = f2add(f2add(f2add(t[5],t[6]), f2add(t[7],t[8])), f2add(t[9],t[10]));
            {
                float2 fu = f2sub(f2add(lo, hi), t[5]);
                *(h2*)&S6A [2 * lane] = __builtin_amdgcn_cvt_pkrtz(lo.x + 0.06f, lo.y + 0.06f);
                *(h2*)&fulA[2 * lane] = __builtin_amdgcn_cvt_pkrtz(fu.x + 0.11f, fu.y + 0.11f);
            }
            #pragma unroll
            for (int k = 1; k < 21; ++k) {
                if (k < 16) t[k+10] = loadrow(k + 10);
                lo = f2sub(f2add(lo, t[k+5]), t[k-1]);
                *(h2*)&S6A[k * SH + 2 * lane] = __builtin_amdgcn_cvt_pkrtz(lo.x + 0.06f, lo.y + 0.06f);
                if (k < 16) {
                    hi = f2sub(f2add(hi, t[k+10]), t[k+4]);
                    float2 fu = f2sub(f2add(lo, hi), t[k+5]);
                    *(h2*)&fulA[k * SH + 2 * lane] = __builtin_amdgcn_cvt_pkrtz(fu.x + 0.11f, fu.y + 0.11f);
                }
            }
        };

        if (by >= 1 && by <= 30 && bx >= 1 && bx <= 6) {
            body([&](int j) {
                return *(const float2*)(xb + (size_t)(Y0 - 5 + j) * N + gc);
            });
        } else {
            const bool vec = (gc >= 0) && (gc <= N - 2);
            body([&](int j) {
                int gr = Y0 - 5 + j;
                gr = gr < 0 ? -gr : (gr > N-1 ? 2*(N-1) - gr : gr);
                const float* rowp = xb + (size_t)gr * N;
                if (vec) return *(const float2*)(rowp + gc);
                int c0 = gc, c1 = gc + 1;
                c0 = c0 < 0 ? -c0 : (c0 > N-1 ? 2*(N-1) - c0 : c0);
                c1 = c1 < 0 ? -c1 : (c1 > N-1 ? 2*(N-1) - c1 : c1);
                return make_float2(rowp[c0], rowp[c1]);
            });
        }
    }
    __syncthreads();   // single-wave block: compiles to in-wave waitcnt, no coupling

    // ---------------- Phase B: 2 independent 8-px sliding-window strips ------
    // t[i] <-> local col 8*tx + i ; out col o = 8*tx+p uses window t[p+1..p+11]
    const int tx = lane & 7;      // 8 strips of 8 px
    const int ty = lane >> 3;     // 0..7 -> rows ty and ty+8
    #pragma unroll
    for (int s = 0; s < 2; ++s) {
        const int row  = ty + 8 * s;
        const int base = row * SH + 8 * tx;

        float gy1[8], ly[8];
        {   // top6 = S6[row] -> gy1 windows (11-wide)
            float t[20];
            load20(S6A, base, t);
            float g = ((t[1]+t[2])+(t[3]+t[4]))+((t[5]+t[6])+(t[7]+t[8]))+((t[9]+t[10])+t[11]);
            gy1[0] = g;
            #pragma unroll
            for (int p = 1; p < 8; ++p) { g += t[p+11] - t[p]; gy1[p] = g; }
        }
        {   // bot6 = S6[row+5] -> gy2 windows, fold into log ratio
            float t[20];
            load20(S6A, base + 5*SH, t);
            float g = ((t[1]+t[2])+(t[3]+t[4]))+((t[5]+t[6])+(t[7]+t[8]))+((t[9]+t[10])+t[11]);
            ly[0] = __builtin_amdgcn_logf(gy1[0]) - __builtin_amdgcn_logf(g);
            #pragma unroll
            for (int p = 1; p < 8; ++p) {
                g += t[p+11] - t[p];
                ly[p] = __builtin_amdgcn_logf(gy1[p]) - __builtin_amdgcn_logf(g);
            }
        }
        {   // full11 -> gx window pair (6-wide), combine + store
            float t[20];
            load20(fulA, base, t);
            float g1 = ((t[1]+t[2])+(t[3]+t[4]))+(t[5]+t[6]);
            float g2 = ((t[6]+t[7])+(t[8]+t[9]))+(t[10]+t[11]);
            float r8[8];
            #pragma unroll
            for (int p = 0; p < 8; ++p) {
                if (p) {
                    g1 += t[p+6]  - t[p];
                    g2 += t[p+11] - t[p+5];
                }
                float lx = __builtin_amdgcn_logf(g1) - __builtin_amdgcn_logf(g2);
                r8[p] = LN2 * __builtin_amdgcn_sqrtf(lx*lx + ly[p]*ly[p]);
            }
            float* op = outb + (size_t)(Y0 + row) * N + X0 + tx * 8;
            *(float4*)op       = make_float4(r8[0], r8[1], r8[2], r8[3]);
            *(float4*)(op + 4) = make_float4(r8[4], r8[5], r8[6], r8[7]);
        }
    }
}

extern "C" void kernel_launch(void* const* d_in, const int* in_sizes, int n_in,
                              void* d_out, int out_size, void* d_ws, size_t ws_size,
                              hipStream_t stream) {
    const float* x = (const float*)d_in[0];  // (64,1,512,512) fp32
    float* out = (float*)d_out;              // (64,1,512,512) fp32
    dim3 grid(8 * 32 * 64);                  // 64x16 tiles, swizzled in-kernel
    dim3 block(64);
    boxlog_kernel<<<grid, block, 0, stream>>>(x, out);
}